// Round 18
// baseline (41.361 us; speedup 1.0000x reference)
//
#include <hip/hip_runtime.h>

#define H 1024
#define W 1024
#define M 30          // output rows per block (38 pipeline steps)
#define WCOLS 56      // output cols per wave (64 lanes, 4-lane halo each side)
#define BCOLS 224     // 4 waves per block
#define RSTRIPS 36    // 35 real strips (30 rows each) + 1 pad (grid 720 = 8*90)

__device__ __forceinline__ float bpermf(int idx, float v) {
    return __int_as_float(__builtin_amdgcn_ds_bpermute(idx, __float_as_int(v)));
}

struct Lane {
    int ce, cn;           // clamped / nominal column
    bool colIn, outLane;
    int im2, im1, ip1, ip2, ifix;   // bpermute byte indices
};

struct St {               // per-lane register state (all static-indexed)
    float rh[5], gh[5], bh[5], kh[5];   // rgbk history (row = load row)
    float hs[5], hq[5];                 // horizontal 5-sums of luma, luma^2
    float S0w[5], S0x[5], S0y[5], S0z[5];   // per-row tap partial sums
    float S1w[5], S1x[5], S1y[5], S1z[5];
    float S2w[5], S2x[5], S2y[5], S2z[5];
    float vs_sv, vq_sv;                 // frozen vertical sums at row 1023
};

// One pipeline step. it: step index. Load row = y0-4+it (hist slot PH=it%5).
// DO_S: produce S for row c = y0-6+it. DO_OUT: emit output row o = y0-8+it.
template<int PH, bool DO_S, bool DO_OUT>
__device__ __forceinline__ void kstep(int it, int y0, const Lane& L,
    const float* __restrict__ pR, const float* __restrict__ pG,
    const float* __restrict__ pB, const float* __restrict__ pK,
    float* __restrict__ oR, float* __restrict__ oG, float* __restrict__ oB,
    St& S)
{
    const int  lr    = y0 - 4 + it;
    const int  lrc   = min(max(lr, 0), H - 1);
    const bool rowIn = ((unsigned)lr < (unsigned)H);
    const int  base  = lrc << 10;
    float r = pR[base + L.ce], g = pG[base + L.ce];
    float b = pB[base + L.ce], k = pK[base + L.ce];
    S.rh[PH] = r; S.gh[PH] = g; S.bh[PH] = b; S.kh[PH] = k;
    // zero-padded luma (box filter pads with 0 outside the image)
    float l = (rowIn && L.colIn)
                ? fmaf(0.2126f, r, fmaf(0.7152f, g, 0.0722f * b)) : 0.0f;
    float lm2 = bpermf(L.im2, l), lm1 = bpermf(L.im1, l);
    float lp1 = bpermf(L.ip1, l), lp2 = bpermf(L.ip2, l);
    S.hs[PH] = ((lm2 + lm1) + (lp1 + lp2)) + l;
    S.hq[PH] = ((lm2*lm2 + lm1*lm1) + (lp1*lp1 + lp2*lp2)) + l*l;

    if constexpr (DO_S) {
        const int c = y0 - 6 + it;          // row whose S we produce
        float vs = ((S.hs[0] + S.hs[1]) + (S.hs[2] + S.hs[3])) + S.hs[4];
        float vq = ((S.hq[0] + S.hq[1]) + (S.hq[2] + S.hq[3])) + S.hq[4];
        if (c == H - 1) { S.vs_sv = vs; S.vq_sv = vq; }   // bottom edge-
        if (c >  H - 1) { vs = S.vs_sv; vq = S.vq_sv; }   // replicate freeze
        float mean = vs * 0.04f, msq = vq * 0.04f;
        float var  = fabsf(msq - mean * mean);
        constexpr int PC = (PH + 3) % 5;    // slot of row c
        float w = __expf(-var * 64.0f * S.kh[PC]);
        w = bpermf(L.ifix, w);              // x edge-replication of weights
        float pr = w * S.rh[PC], pg = w * S.gh[PC], pb = w * S.bh[PC];
        float w_m1  = bpermf(L.im1, w),  w_p1  = bpermf(L.ip1, w);
        float w_m2  = bpermf(L.im2, w),  w_p2  = bpermf(L.ip2, w);
        float pr_m1 = bpermf(L.im1, pr), pr_p1 = bpermf(L.ip1, pr);
        float pr_m2 = bpermf(L.im2, pr), pr_p2 = bpermf(L.ip2, pr);
        float pg_m1 = bpermf(L.im1, pg), pg_p1 = bpermf(L.ip1, pg);
        float pg_m2 = bpermf(L.im2, pg), pg_p2 = bpermf(L.ip2, pg);
        float pb_m1 = bpermf(L.im1, pb), pb_p1 = bpermf(L.ip1, pb);
        float pb_m2 = bpermf(L.im2, pb), pb_p2 = bpermf(L.ip2, pb);
        S.S0w[PH] = w;             S.S0x[PH] = pr;
        S.S0y[PH] = pg;            S.S0z[PH] = pb;
        S.S1w[PH] = w_m1 + w_p1;   S.S1x[PH] = pr_m1 + pr_p1;
        S.S1y[PH] = pg_m1 + pg_p1; S.S1z[PH] = pb_m1 + pb_p1;
        S.S2w[PH] = w_m2 + w_p2;   S.S2x[PH] = pr_m2 + pr_p2;
        S.S2y[PH] = pg_m2 + pg_p2; S.S2z[PH] = pb_m2 + pb_p2;
    }

    if constexpr (DO_OUT) {
        const int o = y0 - 8 + it;          // output row
        constexpr int PO = (PH + 1) % 5;    // rgbk slot of row o
        float ko = S.kh[PO];
        float t  = __expf(-2.56f * (1.0f - ko));   // t^(dx^2+dy^2) base
        float t1 = t, t4 = (t * t) * (t * t);
        float ctrR = S.rh[PO], ctrG = S.gh[PO], ctrB = S.bh[PO];
        float aR = 0.f, aG = 0.f, aB = 0.f, aW = 0.f;
        // rows o+dy, dy=-2..2 -> S slots (PH+3+dy)%5, row factor t^(dy^2)
#define ROWTERM(SL, F)                                                    \
        { float rw = S.S0w[SL] + t1 * S.S1w[SL] + t4 * S.S2w[SL];         \
          float rx = S.S0x[SL] + t1 * S.S1x[SL] + t4 * S.S2x[SL];         \
          float ry = S.S0y[SL] + t1 * S.S1y[SL] + t4 * S.S2y[SL];         \
          float rz = S.S0z[SL] + t1 * S.S1z[SL] + t4 * S.S2z[SL];         \
          aW = fmaf(F, rw, aW); aR = fmaf(F, rx, aR);                     \
          aG = fmaf(F, ry, aG); aB = fmaf(F, rz, aB); }
        ROWTERM((PH + 1) % 5, t4)
        ROWTERM((PH + 2) % 5, t1)
        ROWTERM((PH + 3) % 5, 1.0f)
        ROWTERM((PH + 4) % 5, t1)
        ROWTERM(PH,           t4)
#undef ROWTERM
        float cb = 16.0f + ko * (0.001f - 16.0f);   // center boost
        aR += cb * ctrR; aG += cb * ctrG; aB += cb * ctrB; aW += cb;
        float inv = __builtin_amdgcn_rcpf(aW);
        if (L.outLane && o < H) {
            int off = (o << 10) + L.cn;
            oR[off] = ctrR + ko * (aR * inv - ctrR);
            oG[off] = ctrG + ko * (aG * inv - ctrG);
            oB[off] = ctrB + ko * (aB * inv - ctrB);
        }
    }
}

__global__ void kuwahara_kernel(const float* __restrict__ inp,
                                float* __restrict__ out) {
    // ---- XCD-aware bijective swizzle over 720 blocks (8 XCDs x 90) ----
    int bid = blockIdx.x;
    int lin = (bid & 7) * 90 + (bid >> 3);
    int img    = lin / 180;
    int r2     = lin - img * 180;
    int cstrip = r2 / RSTRIPS;
    int rstrip = r2 - cstrip * RSTRIPS;
    int y0 = rstrip * M;
    if (y0 >= H) return;                    // pad strips

    const float* __restrict__ pR = inp + ((size_t)(4*img + 0) << 20);
    const float* __restrict__ pG = inp + ((size_t)(4*img + 1) << 20);
    const float* __restrict__ pB = inp + ((size_t)(4*img + 2) << 20);
    const float* __restrict__ pK = inp + ((size_t)(4*img + 3) << 20);
    float* __restrict__ oR = out + ((size_t)(3*img + 0) << 20);
    float* __restrict__ oG = out + ((size_t)(3*img + 1) << 20);
    float* __restrict__ oB = out + ((size_t)(3*img + 2) << 20);

    const int tid = threadIdx.x;
    const int wi  = tid >> 6;
    const int ln  = tid & 63;

    Lane L;
    L.cn     = cstrip * BCOLS + wi * WCOLS - 4 + ln;
    L.ce     = min(max(L.cn, 0), W - 1);
    L.colIn  = ((unsigned)L.cn < (unsigned)W);
    L.outLane= (ln >= 4) && (ln < 60) && L.colIn;
    L.im2  = (ln - 2) << 2;   // bpermute wraps mod 64; wrapped lanes unused
    L.im1  = (ln - 1) << 2;
    L.ip1  = (ln + 1) << 2;
    L.ip2  = (ln + 2) << 2;
    L.ifix = (ln - L.cn + L.ce) << 2;   // lane of clamped column

    St S;
    S.vs_sv = 0.f; S.vq_sv = 0.f;

    // ---- pipeline warmup ----
    // prefill: hsum rows y0-4..y0-1
    kstep<0, false, false>(0, y0, L, pR, pG, pB, pK, oR, oG, oB, S);
    kstep<1, false, false>(1, y0, L, pR, pG, pB, pK, oR, oG, oB, S);
    kstep<2, false, false>(2, y0, L, pR, pG, pB, pK, oR, oG, oB, S);
    kstep<3, false, false>(3, y0, L, pR, pG, pB, pK, oR, oG, oB, S);
    // S warmup: rows y0-2..y0+1
    kstep<4, true,  false>(4, y0, L, pR, pG, pB, pK, oR, oG, oB, S);
    kstep<0, true,  false>(5, y0, L, pR, pG, pB, pK, oR, oG, oB, S);
    kstep<1, true,  false>(6, y0, L, pR, pG, pB, pK, oR, oG, oB, S);
    if (y0 == 0) {
        // top edge-replication: S(row -1) := S(row -2) := S(row 0) (slot 1)
#define CPY(A) S.A[0] = S.A[1]; S.A[4] = S.A[1];
        CPY(S0w) CPY(S0x) CPY(S0y) CPY(S0z)
        CPY(S1w) CPY(S1x) CPY(S1y) CPY(S1z)
        CPY(S2w) CPY(S2x) CPY(S2y) CPY(S2z)
#undef CPY
    }
    kstep<2, true,  false>(7, y0, L, pR, pG, pB, pK, oR, oG, oB, S);

    // ---- main loop: 30 output rows, unrolled by 5 (static history phases) ----
#pragma unroll 1
    for (int itb = 8; itb < 8 + M; itb += 5) {
        kstep<3, true, true>(itb + 0, y0, L, pR, pG, pB, pK, oR, oG, oB, S);
        kstep<4, true, true>(itb + 1, y0, L, pR, pG, pB, pK, oR, oG, oB, S);
        kstep<0, true, true>(itb + 2, y0, L, pR, pG, pB, pK, oR, oG, oB, S);
        kstep<1, true, true>(itb + 3, y0, L, pR, pG, pB, pK, oR, oG, oB, S);
        kstep<2, true, true>(itb + 4, y0, L, pR, pG, pB, pK, oR, oG, oB, S);
    }
}

extern "C" void kernel_launch(void* const* d_in, const int* in_sizes, int n_in,
                              void* d_out, int out_size, void* d_ws, size_t ws_size,
                              hipStream_t stream) {
    const float* inp = (const float*)d_in[0];
    float* out = (float*)d_out;
    hipLaunchKernelGGL(kuwahara_kernel, dim3(720), dim3(256), 0, stream, inp, out);
}